// Round 12
// baseline (952.427 us; speedup 1.0000x reference)
//
#include <hip/hip_runtime.h>
#include <math.h>

// Problem constants
#define B_    512
#define W_    4
#define KD_   64
#define NC_   32
#define D_    256
#define NN_   16
#define NH_   8
#define AD_   32
#define HOPS_ 4
#define DH_   32
#define DFF_  1024
#define P_    2560
#define BW_   2048   // B*W
#define MAXT_ 56     // worst-case M-tiles: P/64 + (NN-1)

#define INV_SQRT_DH 0.17677669529663687f  // 1/sqrt(32)

// ---------------- block-wide sum over 256 threads ----------------
__device__ __forceinline__ float block_sum256(float v, float* red) {
#pragma unroll
  for (int off = 32; off > 0; off >>= 1) v += __shfl_xor(v, off, 64);
  int wid = threadIdx.x >> 6;
  if ((threadIdx.x & 63) == 0) red[wid] = v;
  __syncthreads();
  float s = red[0] + red[1] + red[2] + red[3];
  __syncthreads();
  return s;
}

__device__ __forceinline__ float gelu_tanh(float v) {
  float u = 0.7978845608028654f * (v + 0.044715f * v * v * v);
  return 0.5f * v * (1.0f + tanhf(u));
}

// ---------------- encode writers + queries -> h, node ----------------
__global__ __launch_bounds__(256) void encode_kernel(
    const float* __restrict__ query_keys, const float* __restrict__ writer_keys,
    const float* __restrict__ kpw, const float* __restrict__ kpb,
    const float* __restrict__ ce, const float* __restrict__ re,
    const float* __restrict__ sne, const float* __restrict__ ilg,
    const float* __restrict__ ilb, const int* __restrict__ qsn,
    const int* __restrict__ wl, const int* __restrict__ wsn,
    float* __restrict__ h, int* __restrict__ node) {
  int p = blockIdx.x, t = threadIdx.x;
  __shared__ float fk[KD_];
  __shared__ float red[4];
  const float* key;
  int lab = -1, sn, role;
  if (p < BW_) { key = writer_keys + (size_t)p * KD_; lab = wl[p]; sn = wsn[p]; role = 0; }
  else { int b = p - BW_; key = query_keys + (size_t)b * KD_; sn = qsn[b]; role = 1; }
  if (t < KD_) fk[t] = key[t];
  __syncthreads();

  float acc = kpb[t] + sne[sn * D_ + t] + re[role * D_ + t];
  if (lab >= 0) acc += ce[lab * D_ + t];
#pragma unroll 8
  for (int i = 0; i < KD_; i++) acc += fk[i] * kpw[i * D_ + t];

  float mean = block_sum256(acc, red) * (1.0f / D_);
  float d = acc - mean;
  float var = block_sum256(d * d, red) * (1.0f / D_);
  float xn = d * (1.0f / sqrtf(var + 1e-5f));

  float sw = 0.0f;
  if (t < KD_) sw = fk[t];
  else if (lab >= 0 && t < KD_ + NC_) sw = (t - KD_ == lab) ? 1.0f : 0.0f;

  h[(size_t)p * D_ + t] = xn * ilg[t] + ilb[t] + sw;
  if (t == 0) node[p] = sn;
}

// ---------------- group packets by node + tile worklist + inverse map -------
__global__ __launch_bounds__(256) void sort_kernel(const int* __restrict__ node,
                                                   int* __restrict__ order,
                                                   int* __restrict__ invord,
                                                   int* __restrict__ offs,
                                                   int* __restrict__ cnts,
                                                   int* __restrict__ tnode,
                                                   int* __restrict__ tstart,
                                                   int* __restrict__ tend,
                                                   int* __restrict__ ntiles) {
  __shared__ int c[NN_], o[NN_], cur[NN_];
  int t = threadIdx.x;
  if (t < NN_) c[t] = 0;
  __syncthreads();
  for (int p = t; p < P_; p += 256) atomicAdd(&c[node[p]], 1);
  __syncthreads();
  if (t == 0) {
    int s = 0;
    for (int n = 0; n < NN_; n++) { o[n] = s; cur[n] = s; s += c[n]; }
    int idx = 0;
    for (int n = 0; n < NN_; n++) {
      int e = o[n] + c[n];
      for (int m0 = o[n]; m0 < e; m0 += 64) {
        tnode[idx] = n; tstart[idx] = m0; tend[idx] = e; idx++;
      }
    }
    ntiles[0] = idx;
  }
  __syncthreads();
  if (t < NN_) { cnts[t] = c[t]; offs[t] = o[t]; }
  for (int p = t; p < P_; p += 256) {
    int r = atomicAdd(&cur[node[p]], 1);
    order[r] = p;
    invord[p] = r;
  }
}

// ---------------- LN with per-node affine, wave-per-row, SORTED out ---------
// 4 rows/block, one wave per row: float4 loads, shuffle-only reduction,
// no __syncthreads.
__global__ __launch_bounds__(256) void ln_affine(const float* __restrict__ h,
                                                 const float* __restrict__ g,
                                                 const float* __restrict__ b,
                                                 const int* __restrict__ node,
                                                 const int* __restrict__ order,
                                                 float* __restrict__ x) {
  int sp = blockIdx.x * 4 + (threadIdx.x >> 6);
  int lane = threadIdx.x & 63;
  int p = order[sp];
  int n = node[p];
  float4 v = *(const float4*)&h[(size_t)p * D_ + lane * 4];
  float s = v.x + v.y + v.z + v.w;
#pragma unroll
  for (int off = 32; off > 0; off >>= 1) s += __shfl_xor(s, off, 64);
  float mean = s * (1.0f / D_);
  float4 d = make_float4(v.x - mean, v.y - mean, v.z - mean, v.w - mean);
  float vr = d.x * d.x + d.y * d.y + d.z * d.z + d.w * d.w;
#pragma unroll
  for (int off = 32; off > 0; off >>= 1) vr += __shfl_xor(vr, off, 64);
  float inv = 1.0f / sqrtf(vr * (1.0f / D_) + 1e-5f);
  float4 gg = *(const float4*)&g[n * D_ + lane * 4];
  float4 bb = *(const float4*)&b[n * D_ + lane * 4];
  float4 o;
  o.x = d.x * inv * gg.x + bb.x;
  o.y = d.y * inv * gg.y + bb.y;
  o.z = d.z * inv * gg.z + bb.z;
  o.w = d.w * inv * gg.w + bb.w;
  *(float4*)&x[(size_t)sp * D_ + lane * 4] = o;
}

// ---------------- grouped linear (R11 winner: JT=64 heavies) ----------------
// 256 threads, MT=64 x JT (64|128); thread tile 4 x (JT/16); JT=128 cols split
// {jc4, jc4+64}. KSPLIT: z=0 main, z=1 raw partial -> pbuf (sorted space),
// folded downstream (no atomics). XMODE: 0 plain x; 1 x[p]+xaux[invord[p]].
template <int DIN, int DOUT, int JT, int ACT, int RESID, int PER_NODE, int KSPLIT, int XMODE>
__global__ __launch_bounds__(256) void glin(const float* __restrict__ x,
                                            const float* __restrict__ W,
                                            const float* __restrict__ bias,
                                            float* __restrict__ out,
                                            float* __restrict__ pbuf,
                                            const float* __restrict__ xaux,
                                            const int* __restrict__ order,
                                            const int* __restrict__ invord,
                                            const int* __restrict__ tnode,
                                            const int* __restrict__ tstart,
                                            const int* __restrict__ tend,
                                            const int* __restrict__ ntiles) {
  constexpr int KC = 32, STX = 68;
  constexpr int CPT = JT / 16;       // cols per thread: 4 or 8
  constexpr int HALF = 64;           // col offset of second half-tile (JT=128)
  constexpr int KLEN = DIN / KSPLIT;
  constexpr int NCH = KLEN / KC;
  constexpr int LPR = JT / 4;        // lanes covering one k-row of W
  constexpr int RPI = 64 / LPR;      // k-rows per 1KB global_load_lds

  int ti = blockIdx.x;
  int n, s0, s1;
  if (PER_NODE) {
    if (ti >= ntiles[0]) return;
    n = tnode[ti]; s0 = tstart[ti]; s1 = tend[ti];
  } else {
    n = 0; s0 = ti * 64; s1 = P_;
  }
  int jbase = blockIdx.y * JT;
  int kz = (KSPLIT > 1) ? blockIdx.z : 0;
  int k0 = kz * KLEN;
  int rows = s1 - s0; if (rows > 64) rows = 64;

  __shared__ float xs[2][KC][STX];
  __shared__ float ws[2][KC][JT];

  int tid = threadIdx.x;
  const float* Wn = W + (size_t)n * DIN * DOUT + jbase;

  // x staging: row = tid>>2, k-quads {tid&3, (tid&3)+4}
  int xrow = tid >> 2, xq = tid & 3;
  bool xvalid = xrow < rows;
  const float* xptr = x + (size_t)(s0 + (xvalid ? xrow : 0)) * DIN + k0 + xq * 4;
  const float* aptr = nullptr;
  if (XMODE == 1) {
    int pr = xvalid ? invord[s0 + xrow] : 0;
    aptr = xaux + (size_t)pr * DIN + k0 + xq * 4;
  }

  float4 xr0, xr1;
  auto xfetch = [&](int kc) {
    if (xvalid) {
      xr0 = *(const float4*)(xptr + kc);
      xr1 = *(const float4*)(xptr + kc + 16);
      if (XMODE == 1) {
        float4 p0 = *(const float4*)(aptr + kc);
        float4 p1 = *(const float4*)(aptr + kc + 16);
        xr0.x += p0.x; xr0.y += p0.y; xr0.z += p0.z; xr0.w += p0.w;
        xr1.x += p1.x; xr1.y += p1.y; xr1.z += p1.z; xr1.w += p1.w;
      }
    } else {
      xr0 = make_float4(0.f, 0.f, 0.f, 0.f);
      xr1 = make_float4(0.f, 0.f, 0.f, 0.f);
    }
  };
  auto xstage = [&](int buf) {
    xs[buf][xq * 4 + 0][xrow] = xr0.x;
    xs[buf][xq * 4 + 1][xrow] = xr0.y;
    xs[buf][xq * 4 + 2][xrow] = xr0.z;
    xs[buf][xq * 4 + 3][xrow] = xr0.w;
    xs[buf][xq * 4 + 16][xrow] = xr1.x;
    xs[buf][xq * 4 + 17][xrow] = xr1.y;
    xs[buf][xq * 4 + 18][xrow] = xr1.z;
    xs[buf][xq * 4 + 19][xrow] = xr1.w;
  };
  // W async staging: wave wvw covers k-rows [wvw*8, wvw*8+8)
  int wvw = tid >> 6, lane = tid & 63;
  int wlr = lane / LPR;
  int wlc = (lane % LPR) * 4;
  auto wfetch = [&](int buf, int kc) {
#pragma unroll
    for (int i = 0; i < 8 / RPI; i++) {
      int kr = wvw * 8 + i * RPI;
      const float* g = &Wn[(size_t)(k0 + kc + kr + wlr) * DOUT + wlc];
      __builtin_amdgcn_global_load_lds(
          (const __attribute__((address_space(1))) unsigned int*)g,
          (__attribute__((address_space(3))) unsigned int*)&ws[buf][kr][0],
          16, 0, 0);
    }
  };

  wfetch(0, 0);
  xfetch(0);
  xstage(0);
  __syncthreads();  // drains vmcnt (incl. global_load_lds) before first use

  int r4 = (tid >> 4) * 4;    // my 4 rows
  int jc4 = (tid & 15) * 4;   // my first col quad; second at jc4+HALF (CPT=8)
  float acc[4][CPT];
#pragma unroll
  for (int r = 0; r < 4; r++)
#pragma unroll
    for (int cc = 0; cc < CPT; cc++) acc[r][cc] = 0.f;

  for (int c = 0; c < NCH; c++) {
    int cur = c & 1;
    if (c + 1 < NCH) {
      wfetch(cur ^ 1, (c + 1) * KC);  // async, lands in other buffer
      xfetch((c + 1) * KC);
    }
#pragma unroll 8
    for (int k = 0; k < KC; k++) {
      float4 a = *(const float4*)&xs[cur][k][r4];    // 16-lane broadcast
      float av[4] = {a.x, a.y, a.z, a.w};
      float bv[CPT];
      float4 b0 = *(const float4*)&ws[cur][k][jc4];  // 2-way (free)
      bv[0] = b0.x; bv[1] = b0.y; bv[2] = b0.z; bv[3] = b0.w;
      if (CPT == 8) {
        float4 b1 = *(const float4*)&ws[cur][k][jc4 + HALF];  // 2-way (free)
        bv[4] = b1.x; bv[5] = b1.y; bv[6] = b1.z; bv[7] = b1.w;
      }
#pragma unroll
      for (int r = 0; r < 4; r++)
#pragma unroll
        for (int cc = 0; cc < CPT; cc++) acc[r][cc] += av[r] * bv[cc];
    }
    if (c + 1 < NCH) xstage(cur ^ 1);
    __syncthreads();
  }

  bool main_part = (KSPLIT == 1) || (kz == 0);
  float bbv[CPT];
#pragma unroll
  for (int cc = 0; cc < 4; cc++) bbv[cc] = bias[n * DOUT + jbase + jc4 + cc];
  if (CPT == 8) {
#pragma unroll
    for (int cc = 0; cc < 4; cc++) bbv[4 + cc] = bias[n * DOUT + jbase + jc4 + HALF + cc];
  }

#pragma unroll
  for (int r = 0; r < 4; r++) {
    int lr = r4 + r;
    if (lr >= rows) continue;
    float v[CPT];
    if (main_part) {
#pragma unroll
      for (int cc = 0; cc < CPT; cc++) {
        v[cc] = acc[r][cc] + bbv[cc];
        if (ACT == 1) v[cc] = gelu_tanh(v[cc]);
      }
      if (RESID) {
        int pp = PER_NODE ? order[s0 + lr] : (s0 + lr);
        float* op = &out[(size_t)pp * DOUT + jbase + jc4];
        {
          float4 old = *(const float4*)op;
          *(float4*)op = make_float4(v[0] + old.x, v[1] + old.y, v[2] + old.z, v[3] + old.w);
        }
        if (CPT == 8) {
          float4 old = *(const float4*)(op + HALF);
          *(float4*)(op + HALF) =
              make_float4(v[4] + old.x, v[5] + old.y, v[6] + old.z, v[7] + old.w);
        }
      } else {
        float* op = &out[(size_t)(s0 + lr) * DOUT + jbase + jc4];
        *(float4*)op = make_float4(v[0], v[1], v[2], v[3]);
        if (CPT == 8)
          *(float4*)(op + HALF) = make_float4(v[4], v[5], v[6], v[7]);
      }
    } else {
      // partial: sorted space, raw accumulator (no bias)
      float* op = &pbuf[(size_t)(s0 + lr) * DOUT + jbase + jc4];
      *(float4*)op = make_float4(acc[r][0], acc[r][1], acc[r][2], acc[r][3]);
      if (CPT == 8)
        *(float4*)(op + HALF) = make_float4(acc[r][4], acc[r][5], acc[r][6], acc[r][7]);
    }
  }
}

// ---------------- same-node attention, 64-row Q-tiles, sorted qkv/ao --------
// grid (P/64, NH); 4 lanes/row (8 dims each). Each 32-key K/V tile staged once
// serves 64 q-rows. Row's 4 lanes are wave-contiguous -> ps is wave-coherent.
#define ATS 36  // padded LDS stride (floats): multiple of 4 (float4 align), !=32 (banks)
__global__ __launch_bounds__(256) void attn_kernel(const float* __restrict__ qkv,
                                                   const int* __restrict__ node,
                                                   const int* __restrict__ order,
                                                   const int* __restrict__ offs,
                                                   const int* __restrict__ cnts,
                                                   float* __restrict__ ao) {
  __shared__ float qs[64 * ATS];   // Q row-major [r][d]
  __shared__ float kts[32 * ATS];  // K transposed [d][j]
  __shared__ float vs[32 * ATS];   // V row-major [j][d]
  __shared__ float ps[64 * ATS];   // P row-major [r][j]
  __shared__ int glo[64], ghi[64];

  int t = threadIdx.x;
  int r = t >> 2;          // my q-row 0..63
  int jq = (t & 3) * 8;    // my 8 score-cols == my 8 output dims
  int r0 = blockIdx.x * 64;
  int hd = blockIdx.y;

  if (t < 64) {
    int n = node[order[r0 + t]];
    glo[t] = offs[n];
    ghi[t] = offs[n] + cnts[n];
  }
  __syncthreads();

  {  // Q tile: sorted row r0+r, 8 dims, wave-coherent with its consumers
    const float* qp = &qkv[(size_t)(r0 + r) * 768 + hd * 32 + jq];
    float4 qa = *(const float4*)qp;
    float4 qb = *(const float4*)(qp + 4);
    qa.x *= INV_SQRT_DH; qa.y *= INV_SQRT_DH; qa.z *= INV_SQRT_DH; qa.w *= INV_SQRT_DH;
    qb.x *= INV_SQRT_DH; qb.y *= INV_SQRT_DH; qb.z *= INV_SQRT_DH; qb.w *= INV_SQRT_DH;
    *(float4*)&qs[r * ATS + jq] = qa;
    *(float4*)&qs[r * ATS + jq + 4] = qb;
  }

  int lo = glo[0];
  int hi = ghi[63];
  int myglo = glo[r], myghi = ghi[r];

  float o[8];
#pragma unroll
  for (int i = 0; i < 8; i++) o[i] = 0.f;
  float mrow = -1e30f, lrow = 0.f;

  int kr = t >> 3;         // staging key-row 0..31
  int kd = (t & 7) * 4;    // staging dims

  for (int kt = lo; kt < hi; kt += 32) {
    int sj = kt + kr;
    float4 k4 = {0.f, 0.f, 0.f, 0.f}, v4 = {0.f, 0.f, 0.f, 0.f};
    if (sj < hi) {
      const float* kp = &qkv[(size_t)sj * 768 + 256 + hd * 32 + kd];
      k4 = *(const float4*)kp;
      v4 = *(const float4*)(kp + 256);
    }
    __syncthreads();  // previous tile's kts/vs reads complete
    kts[(kd + 0) * ATS + kr] = k4.x;
    kts[(kd + 1) * ATS + kr] = k4.y;
    kts[(kd + 2) * ATS + kr] = k4.z;
    kts[(kd + 3) * ATS + kr] = k4.w;
    *(float4*)&vs[kr * ATS + kd] = v4;
    __syncthreads();

    // scores: 8 cols per thread, dot over 32 dims
    float s[8];
#pragma unroll
    for (int i = 0; i < 8; i++) s[i] = 0.f;
#pragma unroll 8
    for (int d = 0; d < 32; d++) {
      float qv = qs[r * ATS + d];
      float4 ka = *(const float4*)&kts[d * ATS + jq];
      float4 kb = *(const float4*)&kts[d * ATS + jq + 4];
      s[0] += qv * ka.x; s[1] += qv * ka.y; s[2] += qv * ka.z; s[3] += qv * ka.w;
      s[4] += qv * kb.x; s[5] += qv * kb.y; s[6] += qv * kb.z; s[7] += qv * kb.w;
    }
    int c0 = kt + jq;
#pragma unroll
    for (int i = 0; i < 8; i++)
      if (c0 + i < myglo || c0 + i >= myghi) s[i] = -1e30f;

    // online softmax: reduce over the row's 4 lanes (width-4 xor shuffles)
    float mx = s[0];
#pragma unroll
    for (int i = 1; i < 8; i++) mx = fmaxf(mx, s[i]);
    mx = fmaxf(mx, __shfl_xor(mx, 1, 4));
    mx = fmaxf(mx, __shfl_xor(mx, 2, 4));
    float mnew = fmaxf(mrow, mx);
    float alpha = __expf(mrow - mnew);
    float pv[8], ls = 0.f;
#pragma unroll
    for (int i = 0; i < 8; i++) { pv[i] = __expf(s[i] - mnew); ls += pv[i]; }
    ls += __shfl_xor(ls, 1, 4);
    ls += __shfl_xor(ls, 2, 4);
    lrow = lrow * alpha + ls;
    mrow = mnew;
#pragma unroll
    for (int i = 0; i < 8; i++) o[i] *= alpha;

    // P -> LDS (row written & read by the same 4 wave-contiguous lanes)
    *(float4*)&ps[r * ATS + jq] = make_float4(pv[0], pv[1], pv[2], pv[3]);
    *(float4*)&ps[r * ATS + jq + 4] = make_float4(pv[4], pv[5], pv[6], pv[7]);
#pragma unroll 8
    for (int j = 0; j < 32; j++) {
      float pj = ps[r * ATS + j];
      float4 va = *(const float4*)&vs[j * ATS + jq];
      float4 vb = *(const float4*)&vs[j * ATS + jq + 4];
      o[0] += pj * va.x; o[1] += pj * va.y; o[2] += pj * va.z; o[3] += pj * va.w;
      o[4] += pj * vb.x; o[5] += pj * vb.y; o[6] += pj * vb.z; o[7] += pj * vb.w;
    }
  }

  float inv = 1.f / lrow;
  float* op = &ao[(size_t)(r0 + r) * D_ + hd * 32 + jq];
  *(float4*)op = make_float4(o[0] * inv, o[1] * inv, o[2] * inv, o[3] * inv);
  *(float4*)(op + 4) = make_float4(o[4] * inv, o[5] * inv, o[6] * inv, o[7] * inv);
}

// ---------------- routing (folds fc2 split-K partial): -----------------------
// hv = h[p] + pbuf[inv[p]]; dir/argmax/mag on hv; h[p] = hv + delta*sigmoid(mag)
__global__ __launch_bounds__(256) void route_kernel(float* __restrict__ h,
                                                    const float* __restrict__ pbuf,
                                                    const int* __restrict__ invord,
                                                    const float* __restrict__ dir_w,
                                                    const float* __restrict__ dir_b,
                                                    const float* __restrict__ at,
                                                    const float* __restrict__ mag_w,
                                                    const float* __restrict__ mag_b,
                                                    const float* __restrict__ delta,
                                                    int* __restrict__ node) {
  int p = blockIdx.x, t = threadIdx.x;
  __shared__ float hs[D_];
  __shared__ float dpart[8][AD_];
  __shared__ float dirs[AD_];
  __shared__ float scs[NN_];
  __shared__ float red[4];
  float hv = h[(size_t)p * D_ + t] + pbuf[(size_t)invord[p] * D_ + t];
  hs[t] = hv;
  __syncthreads();

  int j = t & 31, seg = t >> 5;
  float part = 0.0f;
#pragma unroll 8
  for (int i = 0; i < 32; i++) {
    int ii = seg * 32 + i;
    part += hs[ii] * dir_w[ii * D_ + j];
  }
  dpart[seg][j] = part;
  __syncthreads();
  if (t < AD_) {
    float s = dir_b[t];
#pragma unroll
    for (int g = 0; g < 8; g++) s += dpart[g][t];
    dirs[t] = s;
  }
  __syncthreads();
  if (t < NN_) {
    float s = 0.0f;
#pragma unroll
    for (int a = 0; a < AD_; a++) s += dirs[a] * at[t * AD_ + a];
    scs[t] = s;
  }
  __syncthreads();
  if (t == 0) {
    float best = scs[0];
    int arg = 0;
    for (int nn = 1; nn < NN_; nn++)
      if (scs[nn] > best) { best = scs[nn]; arg = nn; }  // first-max like jnp.argmax
    node[p] = arg;
  }
  float mag = block_sum256(hv * mag_w[t], red) + mag_b[0];
  float sig = 1.0f / (1.0f + __expf(-mag));
  h[(size_t)p * D_ + t] = hv + delta[(size_t)p * D_ + t] * sig;
}

// ---------------- final logits ----------------
__global__ __launch_bounds__(256) void out_kernel(const float* __restrict__ h,
                                                  const float* __restrict__ ow,
                                                  const float* __restrict__ ob,
                                                  float* __restrict__ out) {
  int p = blockIdx.x, t = threadIdx.x;
  __shared__ float hs[D_];
  __shared__ float part[8][NC_];
  hs[t] = h[(size_t)p * D_ + t];
  __syncthreads();
  int j = t & 31, seg = t >> 5;
  float s = 0.0f;
#pragma unroll 8
  for (int i = 0; i < 32; i++) {
    int ii = seg * 32 + i;
    s += hs[ii] * ow[ii * NC_ + j];
  }
  part[seg][j] = s;
  __syncthreads();
  if (t < NC_) {
    float r = ob[t];
#pragma unroll
    for (int g = 0; g < 8; g++) r += part[g][t];
    out[(size_t)p * NC_ + t] = r;
  }
}

extern "C" void kernel_launch(void* const* d_in, const int* in_sizes, int n_in,
                              void* d_out, int out_size, void* d_ws, size_t ws_size,
                              hipStream_t stream) {
  (void)in_sizes; (void)n_in; (void)out_size; (void)ws_size;
  const float* query_keys       = (const float*)d_in[0];
  const float* writer_keys      = (const float*)d_in[1];
  const float* key_proj_w       = (const float*)d_in[2];
  const float* key_proj_b       = (const float*)d_in[3];
  const float* class_embed      = (const float*)d_in[4];
  const float* role_embed       = (const float*)d_in[5];
  const float* start_node_embed = (const float*)d_in[6];
  const float* input_ln_g       = (const float*)d_in[7];
  const float* input_ln_b       = (const float*)d_in[8];
  const float* ln1_g            = (const float*)d_in[9];
  const float* ln1_b            = (const float*)d_in[10];
  const float* wqkv             = (const float*)d_in[11];
  const float* bqkv             = (const float*)d_in[12];
  const float* wo               = (const float*)d_in[13];
  const float* bo               = (const float*)d_in[14];
  const float* ln2_g            = (const float*)d_in[15];
  const float* ln2_b            = (const float*)d_in[16];
  const float* w_fc1            = (const float*)d_in[17];
  const float* b_fc1            = (const float*)d_in[18];
  const float* w_fc2            = (const float*)d_in[19];
  const float* b_fc2            = (const float*)d_in[20];
  const float* delta_w          = (const float*)d_in[21];
  const float* delta_b          = (const float*)d_in[22];
  const float* dir_w            = (const float*)d_in[23];
  const float* dir_b            = (const float*)d_in[24];
  const float* mag_w            = (const float*)d_in[25];
  const float* mag_b            = (const float*)d_in[26];
  const float* out_w            = (const float*)d_in[27];
  const float* out_b            = (const float*)d_in[28];
  const float* address_table    = (const float*)d_in[29];
  const int* query_start_nodes  = (const int*)d_in[30];
  const int* writer_labels      = (const int*)d_in[31];
  const int* writer_start_nodes = (const int*)d_in[32];

  uintptr_t basep = (uintptr_t)d_ws;
  auto carve = [&](size_t bytes) {
    basep = (basep + 255) & ~(uintptr_t)255;
    void* r = (void*)basep;
    basep += bytes;
    return r;
  };
  // Buffer roles:
  //  h    : packet-space residual stream
  //  x    : sorted space: ln output / attn output (ao)
  //  buf1 : sorted qkv main [P x 768]; reused as delta out [P x 256]
  //  ff   : sorted fc1 output [P x 1024]
  //  pbuf : fc2 z1 partial [P x 256] (folded by delta-glin XMODE=1 and route)
  float* h    = (float*)carve((size_t)P_ * D_ * 4);
  float* x    = (float*)carve((size_t)P_ * D_ * 4);
  float* buf1 = (float*)carve((size_t)P_ * DFF_ * 4);
  float* ff   = (float*)carve((size_t)P_ * DFF_ * 4);
  float* pbuf = (float*)carve((size_t)P_ * D_ * 4);
  int* node   = (int*)carve(P_ * 4);
  int* order  = (int*)carve(P_ * 4);
  int* invord = (int*)carve(P_ * 4);
  int* offs   = (int*)carve(NN_ * 4);
  int* cnts   = (int*)carve(NN_ * 4);
  int* tnode  = (int*)carve(MAXT_ * 4);
  int* tstart = (int*)carve(MAXT_ * 4);
  int* tend   = (int*)carve(MAXT_ * 4);
  int* ntiles = (int*)carve(4);

  encode_kernel<<<P_, 256, 0, stream>>>(query_keys, writer_keys, key_proj_w, key_proj_b,
                                        class_embed, role_embed, start_node_embed,
                                        input_ln_g, input_ln_b, query_start_nodes,
                                        writer_labels, writer_start_nodes, h, node);

  for (int hop = 0; hop < HOPS_; ++hop) {
    sort_kernel<<<1, 256, 0, stream>>>(node, order, invord, offs, cnts,
                                       tnode, tstart, tend, ntiles);
    ln_affine<<<P_ / 4, 256, 0, stream>>>(h, ln1_g, ln1_b, node, order, x);
    glin<256, 768, 64, 0, 0, 1, 1, 0><<<dim3(MAXT_, 12), 256, 0, stream>>>(
        x, wqkv, bqkv, buf1, nullptr, nullptr, order, invord, tnode, tstart, tend,
        ntiles);
    attn_kernel<<<dim3(P_ / 64, NH_), 256, 0, stream>>>(buf1, node, order, offs,
                                                        cnts, x /*ao, sorted*/);
    glin<256, 256, 64, 0, 1, 1, 1, 0><<<dim3(MAXT_, 4), 256, 0, stream>>>(
        x, wo, bo, h, nullptr, nullptr, order, invord, tnode, tstart, tend, ntiles);
    ln_affine<<<P_ / 4, 256, 0, stream>>>(h, ln2_g, ln2_b, node, order, x);
    glin<256, 1024, 64, 1, 0, 1, 1, 0><<<dim3(MAXT_, 16), 256, 0, stream>>>(
        x, w_fc1, b_fc1, ff, nullptr, nullptr, order, invord, tnode, tstart, tend,
        ntiles);
    glin<1024, 256, 64, 0, 1, 1, 2, 0><<<dim3(MAXT_, 4, 2), 256, 0, stream>>>(
        ff, w_fc2, b_fc2, h, pbuf, nullptr, order, invord, tnode, tstart, tend,
        ntiles);
    // delta = (h + pbuf) @ delta_w + delta_b   (dense, packet space, XMODE=1)
    glin<256, 256, 64, 0, 0, 0, 1, 1><<<dim3(P_ / 64, 4), 256, 0, stream>>>(
        h, delta_w, delta_b, buf1 /*delta out*/, nullptr, pbuf, order, invord,
        tnode, tstart, tend, ntiles);
    route_kernel<<<P_, 256, 0, stream>>>(h, pbuf, invord, dir_w, dir_b, address_table,
                                         mag_w, mag_b, buf1, node);
  }

  out_kernel<<<P_, 256, 0, stream>>>(h, out_w, out_b, (float*)d_out);
}

// Round 13
// 904.853 us; speedup vs baseline: 1.0526x; 1.0526x over previous
//
#include <hip/hip_runtime.h>
#include <math.h>

// Problem constants
#define B_    512
#define W_    4
#define KD_   64
#define NC_   32
#define D_    256
#define NN_   16
#define NH_   8
#define AD_   32
#define HOPS_ 4
#define DH_   32
#define DFF_  1024
#define P_    2560
#define BW_   2048   // B*W
#define MAXT_ 56     // worst-case M-tiles: P/64 + (NN-1)

#define INV_SQRT_DH 0.17677669529663687f  // 1/sqrt(32)

// ---------------- block-wide sum over 256 threads ----------------
__device__ __forceinline__ float block_sum256(float v, float* red) {
#pragma unroll
  for (int off = 32; off > 0; off >>= 1) v += __shfl_xor(v, off, 64);
  int wid = threadIdx.x >> 6;
  if ((threadIdx.x & 63) == 0) red[wid] = v;
  __syncthreads();
  float s = red[0] + red[1] + red[2] + red[3];
  __syncthreads();
  return s;
}

__device__ __forceinline__ float gelu_tanh(float v) {
  float u = 0.7978845608028654f * (v + 0.044715f * v * v * v);
  return 0.5f * v * (1.0f + tanhf(u));
}

// ---------------- encode writers + queries -> h, node ----------------
__global__ __launch_bounds__(256) void encode_kernel(
    const float* __restrict__ query_keys, const float* __restrict__ writer_keys,
    const float* __restrict__ kpw, const float* __restrict__ kpb,
    const float* __restrict__ ce, const float* __restrict__ re,
    const float* __restrict__ sne, const float* __restrict__ ilg,
    const float* __restrict__ ilb, const int* __restrict__ qsn,
    const int* __restrict__ wl, const int* __restrict__ wsn,
    float* __restrict__ h, int* __restrict__ node) {
  int p = blockIdx.x, t = threadIdx.x;
  __shared__ float fk[KD_];
  __shared__ float red[4];
  const float* key;
  int lab = -1, sn, role;
  if (p < BW_) { key = writer_keys + (size_t)p * KD_; lab = wl[p]; sn = wsn[p]; role = 0; }
  else { int b = p - BW_; key = query_keys + (size_t)b * KD_; sn = qsn[b]; role = 1; }
  if (t < KD_) fk[t] = key[t];
  __syncthreads();

  float acc = kpb[t] + sne[sn * D_ + t] + re[role * D_ + t];
  if (lab >= 0) acc += ce[lab * D_ + t];
#pragma unroll 8
  for (int i = 0; i < KD_; i++) acc += fk[i] * kpw[i * D_ + t];

  float mean = block_sum256(acc, red) * (1.0f / D_);
  float d = acc - mean;
  float var = block_sum256(d * d, red) * (1.0f / D_);
  float xn = d * (1.0f / sqrtf(var + 1e-5f));

  float sw = 0.0f;
  if (t < KD_) sw = fk[t];
  else if (lab >= 0 && t < KD_ + NC_) sw = (t - KD_ == lab) ? 1.0f : 0.0f;

  h[(size_t)p * D_ + t] = xn * ilg[t] + ilb[t] + sw;
  if (t == 0) node[p] = sn;
}

// ---------------- group packets by node + tile worklist + inverse map -------
__global__ __launch_bounds__(256) void sort_kernel(const int* __restrict__ node,
                                                   int* __restrict__ order,
                                                   int* __restrict__ invord,
                                                   int* __restrict__ offs,
                                                   int* __restrict__ cnts,
                                                   int* __restrict__ tnode,
                                                   int* __restrict__ tstart,
                                                   int* __restrict__ tend,
                                                   int* __restrict__ ntiles) {
  __shared__ int c[NN_], o[NN_], cur[NN_];
  int t = threadIdx.x;
  if (t < NN_) c[t] = 0;
  __syncthreads();
  for (int p = t; p < P_; p += 256) atomicAdd(&c[node[p]], 1);
  __syncthreads();
  if (t == 0) {
    int s = 0;
    for (int n = 0; n < NN_; n++) { o[n] = s; cur[n] = s; s += c[n]; }
    int idx = 0;
    for (int n = 0; n < NN_; n++) {
      int e = o[n] + c[n];
      for (int m0 = o[n]; m0 < e; m0 += 64) {
        tnode[idx] = n; tstart[idx] = m0; tend[idx] = e; idx++;
      }
    }
    ntiles[0] = idx;
  }
  __syncthreads();
  if (t < NN_) { cnts[t] = c[t]; offs[t] = o[t]; }
  for (int p = t; p < P_; p += 256) {
    int r = atomicAdd(&cur[node[p]], 1);
    order[r] = p;
    invord[p] = r;
  }
}

// ---------------- LN with per-node affine, wave-per-row, SORTED out ---------
// 4 rows/block, one wave per row: float4 loads, shuffle-only reduction,
// no __syncthreads.
__global__ __launch_bounds__(256) void ln_affine(const float* __restrict__ h,
                                                 const float* __restrict__ g,
                                                 const float* __restrict__ b,
                                                 const int* __restrict__ node,
                                                 const int* __restrict__ order,
                                                 float* __restrict__ x) {
  int sp = blockIdx.x * 4 + (threadIdx.x >> 6);
  int lane = threadIdx.x & 63;
  int p = order[sp];
  int n = node[p];
  float4 v = *(const float4*)&h[(size_t)p * D_ + lane * 4];
  float s = v.x + v.y + v.z + v.w;
#pragma unroll
  for (int off = 32; off > 0; off >>= 1) s += __shfl_xor(s, off, 64);
  float mean = s * (1.0f / D_);
  float4 d = make_float4(v.x - mean, v.y - mean, v.z - mean, v.w - mean);
  float vr = d.x * d.x + d.y * d.y + d.z * d.z + d.w * d.w;
#pragma unroll
  for (int off = 32; off > 0; off >>= 1) vr += __shfl_xor(vr, off, 64);
  float inv = 1.0f / sqrtf(vr * (1.0f / D_) + 1e-5f);
  float4 gg = *(const float4*)&g[n * D_ + lane * 4];
  float4 bb = *(const float4*)&b[n * D_ + lane * 4];
  float4 o;
  o.x = d.x * inv * gg.x + bb.x;
  o.y = d.y * inv * gg.y + bb.y;
  o.z = d.z * inv * gg.z + bb.z;
  o.w = d.w * inv * gg.w + bb.w;
  *(float4*)&x[(size_t)sp * D_ + lane * 4] = o;
}

// ---------------- grouped linear (R11 winner: JT=64 heavies) ----------------
// 256 threads, MT=64 x JT (64|128); thread tile 4 x (JT/16); JT=128 cols split
// {jc4, jc4+64}. KSPLIT: z=0 main, z=1 raw partial -> pbuf (sorted space),
// folded downstream (no atomics). XMODE: 0 plain x; 1 x[p]+xaux[invord[p]].
template <int DIN, int DOUT, int JT, int ACT, int RESID, int PER_NODE, int KSPLIT, int XMODE>
__global__ __launch_bounds__(256) void glin(const float* __restrict__ x,
                                            const float* __restrict__ W,
                                            const float* __restrict__ bias,
                                            float* __restrict__ out,
                                            float* __restrict__ pbuf,
                                            const float* __restrict__ xaux,
                                            const int* __restrict__ order,
                                            const int* __restrict__ invord,
                                            const int* __restrict__ tnode,
                                            const int* __restrict__ tstart,
                                            const int* __restrict__ tend,
                                            const int* __restrict__ ntiles) {
  constexpr int KC = 32, STX = 68;
  constexpr int CPT = JT / 16;       // cols per thread: 4 or 8
  constexpr int HALF = 64;           // col offset of second half-tile (JT=128)
  constexpr int KLEN = DIN / KSPLIT;
  constexpr int NCH = KLEN / KC;
  constexpr int LPR = JT / 4;        // lanes covering one k-row of W
  constexpr int RPI = 64 / LPR;      // k-rows per 1KB global_load_lds

  int ti = blockIdx.x;
  int n, s0, s1;
  if (PER_NODE) {
    if (ti >= ntiles[0]) return;
    n = tnode[ti]; s0 = tstart[ti]; s1 = tend[ti];
  } else {
    n = 0; s0 = ti * 64; s1 = P_;
  }
  int jbase = blockIdx.y * JT;
  int kz = (KSPLIT > 1) ? blockIdx.z : 0;
  int k0 = kz * KLEN;
  int rows = s1 - s0; if (rows > 64) rows = 64;

  __shared__ float xs[2][KC][STX];
  __shared__ float ws[2][KC][JT];

  int tid = threadIdx.x;
  const float* Wn = W + (size_t)n * DIN * DOUT + jbase;

  // x staging: row = tid>>2, k-quads {tid&3, (tid&3)+4}
  int xrow = tid >> 2, xq = tid & 3;
  bool xvalid = xrow < rows;
  const float* xptr = x + (size_t)(s0 + (xvalid ? xrow : 0)) * DIN + k0 + xq * 4;
  const float* aptr = nullptr;
  if (XMODE == 1) {
    int pr = xvalid ? invord[s0 + xrow] : 0;
    aptr = xaux + (size_t)pr * DIN + k0 + xq * 4;
  }

  float4 xr0, xr1;
  auto xfetch = [&](int kc) {
    if (xvalid) {
      xr0 = *(const float4*)(xptr + kc);
      xr1 = *(const float4*)(xptr + kc + 16);
      if (XMODE == 1) {
        float4 p0 = *(const float4*)(aptr + kc);
        float4 p1 = *(const float4*)(aptr + kc + 16);
        xr0.x += p0.x; xr0.y += p0.y; xr0.z += p0.z; xr0.w += p0.w;
        xr1.x += p1.x; xr1.y += p1.y; xr1.z += p1.z; xr1.w += p1.w;
      }
    } else {
      xr0 = make_float4(0.f, 0.f, 0.f, 0.f);
      xr1 = make_float4(0.f, 0.f, 0.f, 0.f);
    }
  };
  auto xstage = [&](int buf) {
    xs[buf][xq * 4 + 0][xrow] = xr0.x;
    xs[buf][xq * 4 + 1][xrow] = xr0.y;
    xs[buf][xq * 4 + 2][xrow] = xr0.z;
    xs[buf][xq * 4 + 3][xrow] = xr0.w;
    xs[buf][xq * 4 + 16][xrow] = xr1.x;
    xs[buf][xq * 4 + 17][xrow] = xr1.y;
    xs[buf][xq * 4 + 18][xrow] = xr1.z;
    xs[buf][xq * 4 + 19][xrow] = xr1.w;
  };
  // W async staging: wave wvw covers k-rows [wvw*8, wvw*8+8)
  int wvw = tid >> 6, lane = tid & 63;
  int wlr = lane / LPR;
  int wlc = (lane % LPR) * 4;
  auto wfetch = [&](int buf, int kc) {
#pragma unroll
    for (int i = 0; i < 8 / RPI; i++) {
      int kr = wvw * 8 + i * RPI;
      const float* g = &Wn[(size_t)(k0 + kc + kr + wlr) * DOUT + wlc];
      __builtin_amdgcn_global_load_lds(
          (const __attribute__((address_space(1))) unsigned int*)g,
          (__attribute__((address_space(3))) unsigned int*)&ws[buf][kr][0],
          16, 0, 0);
    }
  };

  wfetch(0, 0);
  xfetch(0);
  xstage(0);
  __syncthreads();  // drains vmcnt (incl. global_load_lds) before first use

  int r4 = (tid >> 4) * 4;    // my 4 rows
  int jc4 = (tid & 15) * 4;   // my first col quad; second at jc4+HALF (CPT=8)
  float acc[4][CPT];
#pragma unroll
  for (int r = 0; r < 4; r++)
#pragma unroll
    for (int cc = 0; cc < CPT; cc++) acc[r][cc] = 0.f;

  for (int c = 0; c < NCH; c++) {
    int cur = c & 1;
    if (c + 1 < NCH) {
      wfetch(cur ^ 1, (c + 1) * KC);  // async, lands in other buffer
      xfetch((c + 1) * KC);
    }
#pragma unroll 8
    for (int k = 0; k < KC; k++) {
      float4 a = *(const float4*)&xs[cur][k][r4];    // 16-lane broadcast
      float av[4] = {a.x, a.y, a.z, a.w};
      float bv[CPT];
      float4 b0 = *(const float4*)&ws[cur][k][jc4];  // 2-way (free)
      bv[0] = b0.x; bv[1] = b0.y; bv[2] = b0.z; bv[3] = b0.w;
      if (CPT == 8) {
        float4 b1 = *(const float4*)&ws[cur][k][jc4 + HALF];  // 2-way (free)
        bv[4] = b1.x; bv[5] = b1.y; bv[6] = b1.z; bv[7] = b1.w;
      }
#pragma unroll
      for (int r = 0; r < 4; r++)
#pragma unroll
        for (int cc = 0; cc < CPT; cc++) acc[r][cc] += av[r] * bv[cc];
    }
    if (c + 1 < NCH) xstage(cur ^ 1);
    __syncthreads();
  }

  bool main_part = (KSPLIT == 1) || (kz == 0);
  float bbv[CPT];
#pragma unroll
  for (int cc = 0; cc < 4; cc++) bbv[cc] = bias[n * DOUT + jbase + jc4 + cc];
  if (CPT == 8) {
#pragma unroll
    for (int cc = 0; cc < 4; cc++) bbv[4 + cc] = bias[n * DOUT + jbase + jc4 + HALF + cc];
  }

#pragma unroll
  for (int r = 0; r < 4; r++) {
    int lr = r4 + r;
    if (lr >= rows) continue;
    float v[CPT];
    if (main_part) {
#pragma unroll
      for (int cc = 0; cc < CPT; cc++) {
        v[cc] = acc[r][cc] + bbv[cc];
        if (ACT == 1) v[cc] = gelu_tanh(v[cc]);
      }
      if (RESID) {
        int pp = PER_NODE ? order[s0 + lr] : (s0 + lr);
        float* op = &out[(size_t)pp * DOUT + jbase + jc4];
        {
          float4 old = *(const float4*)op;
          *(float4*)op = make_float4(v[0] + old.x, v[1] + old.y, v[2] + old.z, v[3] + old.w);
        }
        if (CPT == 8) {
          float4 old = *(const float4*)(op + HALF);
          *(float4*)(op + HALF) =
              make_float4(v[4] + old.x, v[5] + old.y, v[6] + old.z, v[7] + old.w);
        }
      } else {
        float* op = &out[(size_t)(s0 + lr) * DOUT + jbase + jc4];
        *(float4*)op = make_float4(v[0], v[1], v[2], v[3]);
        if (CPT == 8)
          *(float4*)(op + HALF) = make_float4(v[4], v[5], v[6], v[7]);
      }
    } else {
      // partial: sorted space, raw accumulator (no bias)
      float* op = &pbuf[(size_t)(s0 + lr) * DOUT + jbase + jc4];
      *(float4*)op = make_float4(acc[r][0], acc[r][1], acc[r][2], acc[r][3]);
      if (CPT == 8)
        *(float4*)(op + HALF) = make_float4(acc[r][4], acc[r][5], acc[r][6], acc[r][7]);
    }
  }
}

// ---------------- same-node attention, flash-style, sorted qkv/ao ----------
// R11 version: 32-row Q-tiles, 8 lanes/row, 4 cols each. grid (P/32, NH).
#define ATS 36  // padded LDS stride (floats): multiple of 4 (float4 align), !=32 (banks)
__global__ __launch_bounds__(256) void attn_kernel(const float* __restrict__ qkv,
                                                   const int* __restrict__ node,
                                                   const int* __restrict__ order,
                                                   const int* __restrict__ offs,
                                                   const int* __restrict__ cnts,
                                                   float* __restrict__ ao) {
  __shared__ float qs[32 * ATS];   // Q row-major [r][d]
  __shared__ float kts[32 * ATS];  // K transposed [d][j]
  __shared__ float vs[32 * ATS];   // V row-major [j][d]
  __shared__ float ps[32 * ATS];   // P row-major [r][j] (wave-coherent use)
  __shared__ int glo[32], ghi[32];

  int t = threadIdx.x;
  int r = t >> 3;          // my q-row (and my staging key-row)
  int j4 = (t & 7) * 4;    // my 4 score-cols == my 4 output dims
  int r0 = blockIdx.x * 32;
  int hd = blockIdx.y;

  if (t < 32) {
    int n = node[order[r0 + t]];
    glo[t] = offs[n];
    ghi[t] = offs[n] + cnts[n];
  }
  __syncthreads();

  {  // Q tile: sorted row r0+r, coalesced
    const float* qp = &qkv[(size_t)(r0 + r) * 768 + hd * 32 + j4];
    float4 q4 = *(const float4*)qp;
    q4.x *= INV_SQRT_DH; q4.y *= INV_SQRT_DH; q4.z *= INV_SQRT_DH; q4.w *= INV_SQRT_DH;
    *(float4*)&qs[r * ATS + j4] = q4;
  }

  int lo = glo[0];
  int hi = ghi[31];
  int myglo = glo[r], myghi = ghi[r];

  float4 o4 = {0.f, 0.f, 0.f, 0.f};
  float mrow = -1e30f, lrow = 0.f;

  for (int kt = lo; kt < hi; kt += 32) {
    int sj = kt + r;
    float4 k4 = {0.f, 0.f, 0.f, 0.f}, v4 = {0.f, 0.f, 0.f, 0.f};
    if (sj < hi) {
      const float* kp = &qkv[(size_t)sj * 768 + 256 + hd * 32 + j4];
      k4 = *(const float4*)kp;
      v4 = *(const float4*)(kp + 256);
    }
    __syncthreads();
    kts[(j4 + 0) * ATS + r] = k4.x;
    kts[(j4 + 1) * ATS + r] = k4.y;
    kts[(j4 + 2) * ATS + r] = k4.z;
    kts[(j4 + 3) * ATS + r] = k4.w;
    *(float4*)&vs[r * ATS + j4] = v4;
    __syncthreads();

    float s0 = 0.f, s1 = 0.f, s2 = 0.f, s3 = 0.f;
#pragma unroll 8
    for (int d = 0; d < 32; d++) {
      float qv = qs[r * ATS + d];
      float4 kv = *(const float4*)&kts[d * ATS + j4];
      s0 += qv * kv.x; s1 += qv * kv.y; s2 += qv * kv.z; s3 += qv * kv.w;
    }
    int c0 = kt + j4;
    if (c0 + 0 < myglo || c0 + 0 >= myghi) s0 = -1e30f;
    if (c0 + 1 < myglo || c0 + 1 >= myghi) s1 = -1e30f;
    if (c0 + 2 < myglo || c0 + 2 >= myghi) s2 = -1e30f;
    if (c0 + 3 < myglo || c0 + 3 >= myghi) s3 = -1e30f;

    float mx = fmaxf(fmaxf(s0, s1), fmaxf(s2, s3));
#pragma unroll
    for (int off = 4; off > 0; off >>= 1) mx = fmaxf(mx, __shfl_xor(mx, off, 8));
    float mnew = fmaxf(mrow, mx);
    float alpha = __expf(mrow - mnew);
    float p0 = __expf(s0 - mnew), p1 = __expf(s1 - mnew);
    float p2 = __expf(s2 - mnew), p3 = __expf(s3 - mnew);
    float ls = p0 + p1 + p2 + p3;
#pragma unroll
    for (int off = 4; off > 0; off >>= 1) ls += __shfl_xor(ls, off, 8);
    lrow = lrow * alpha + ls;
    mrow = mnew;
    o4.x *= alpha; o4.y *= alpha; o4.z *= alpha; o4.w *= alpha;

    *(float4*)&ps[r * ATS + j4] = make_float4(p0, p1, p2, p3);
#pragma unroll 8
    for (int j = 0; j < 32; j++) {
      float pj = ps[r * ATS + j];
      float4 vv = *(const float4*)&vs[j * ATS + j4];
      o4.x += pj * vv.x; o4.y += pj * vv.y; o4.z += pj * vv.z; o4.w += pj * vv.w;
    }
  }

  float inv = 1.f / lrow;
  o4.x *= inv; o4.y *= inv; o4.z *= inv; o4.w *= inv;
  *(float4*)&ao[(size_t)(r0 + r) * D_ + hd * 32 + j4] = o4;  // sorted space
}

// ---------------- routing (folds fc2 split-K partial): -----------------------
// hv = h[p] + pbuf[inv[p]]; dir/argmax/mag on hv; h[p] = hv + delta*sigmoid(mag)
__global__ __launch_bounds__(256) void route_kernel(float* __restrict__ h,
                                                    const float* __restrict__ pbuf,
                                                    const int* __restrict__ invord,
                                                    const float* __restrict__ dir_w,
                                                    const float* __restrict__ dir_b,
                                                    const float* __restrict__ at,
                                                    const float* __restrict__ mag_w,
                                                    const float* __restrict__ mag_b,
                                                    const float* __restrict__ delta,
                                                    int* __restrict__ node) {
  int p = blockIdx.x, t = threadIdx.x;
  __shared__ float hs[D_];
  __shared__ float dpart[8][AD_];
  __shared__ float dirs[AD_];
  __shared__ float scs[NN_];
  __shared__ float red[4];
  float hv = h[(size_t)p * D_ + t] + pbuf[(size_t)invord[p] * D_ + t];
  hs[t] = hv;
  __syncthreads();

  int j = t & 31, seg = t >> 5;
  float part = 0.0f;
#pragma unroll 8
  for (int i = 0; i < 32; i++) {
    int ii = seg * 32 + i;
    part += hs[ii] * dir_w[ii * D_ + j];
  }
  dpart[seg][j] = part;
  __syncthreads();
  if (t < AD_) {
    float s = dir_b[t];
#pragma unroll
    for (int g = 0; g < 8; g++) s += dpart[g][t];
    dirs[t] = s;
  }
  __syncthreads();
  if (t < NN_) {
    float s = 0.0f;
#pragma unroll
    for (int a = 0; a < AD_; a++) s += dirs[a] * at[t * AD_ + a];
    scs[t] = s;
  }
  __syncthreads();
  if (t == 0) {
    float best = scs[0];
    int arg = 0;
    for (int nn = 1; nn < NN_; nn++)
      if (scs[nn] > best) { best = scs[nn]; arg = nn; }  // first-max like jnp.argmax
    node[p] = arg;
  }
  float mag = block_sum256(hv * mag_w[t], red) + mag_b[0];
  float sig = 1.0f / (1.0f + __expf(-mag));
  h[(size_t)p * D_ + t] = hv + delta[(size_t)p * D_ + t] * sig;
}

// ---------------- final logits ----------------
__global__ __launch_bounds__(256) void out_kernel(const float* __restrict__ h,
                                                  const float* __restrict__ ow,
                                                  const float* __restrict__ ob,
                                                  float* __restrict__ out) {
  int p = blockIdx.x, t = threadIdx.x;
  __shared__ float hs[D_];
  __shared__ float part[8][NC_];
  hs[t] = h[(size_t)p * D_ + t];
  __syncthreads();
  int j = t & 31, seg = t >> 5;
  float s = 0.0f;
#pragma unroll 8
  for (int i = 0; i < 32; i++) {
    int ii = seg * 32 + i;
    s += hs[ii] * ow[ii * NC_ + j];
  }
  part[seg][j] = s;
  __syncthreads();
  if (t < NC_) {
    float r = ob[t];
#pragma unroll
    for (int g = 0; g < 8; g++) r += part[g][t];
    out[(size_t)p * NC_ + t] = r;
  }
}

extern "C" void kernel_launch(void* const* d_in, const int* in_sizes, int n_in,
                              void* d_out, int out_size, void* d_ws, size_t ws_size,
                              hipStream_t stream) {
  (void)in_sizes; (void)n_in; (void)out_size; (void)ws_size;
  const float* query_keys       = (const float*)d_in[0];
  const float* writer_keys      = (const float*)d_in[1];
  const float* key_proj_w       = (const float*)d_in[2];
  const float* key_proj_b       = (const float*)d_in[3];
  const float* class_embed      = (const float*)d_in[4];
  const float* role_embed       = (const float*)d_in[5];
  const float* start_node_embed = (const float*)d_in[6];
  const float* input_ln_g       = (const float*)d_in[7];
  const float* input_ln_b       = (const float*)d_in[8];
  const float* ln1_g            = (const float*)d_in[9];
  const float* ln1_b            = (const float*)d_in[10];
  const float* wqkv             = (const float*)d_in[11];
  const float* bqkv             = (const float*)d_in[12];
  const float* wo               = (const float*)d_in[13];
  const float* bo               = (const float*)d_in[14];
  const float* ln2_g            = (const float*)d_in[15];
  const float* ln2_b            = (const float*)d_in[16];
  const float* w_fc1            = (const float*)d_in[17];
  const float* b_fc1            = (const float*)d_in[18];
  const float* w_fc2            = (const float*)d_in[19];
  const float* b_fc2            = (const float*)d_in[20];
  const float* delta_w          = (const float*)d_in[21];
  const float* delta_b          = (const float*)d_in[22];
  const float* dir_w            = (const float*)d_in[23];
  const float* dir_b            = (const float*)d_in[24];
  const float* mag_w            = (const float*)d_in[25];
  const float* mag_b            = (const float*)d_in[26];
  const float* out_w            = (const float*)d_in[27];
  const float* out_b            = (const float*)d_in[28];
  const float* address_table    = (const float*)d_in[29];
  const int* query_start_nodes  = (const int*)d_in[30];
  const int* writer_labels      = (const int*)d_in[31];
  const int* writer_start_nodes = (const int*)d_in[32];

  uintptr_t basep = (uintptr_t)d_ws;
  auto carve = [&](size_t bytes) {
    basep = (basep + 255) & ~(uintptr_t)255;
    void* r = (void*)basep;
    basep += bytes;
    return r;
  };
  // Buffer roles:
  //  h    : packet-space residual stream
  //  x    : sorted space: ln output / attn output (ao)
  //  buf1 : sorted qkv main [P x 768]; reused as delta out [P x 256]
  //  ff   : sorted fc1 output [P x 1024]
  //  pbuf : fc2 z1 partial [P x 256] (folded by delta-glin XMODE=1 and route)
  float* h    = (float*)carve((size_t)P_ * D_ * 4);
  float* x    = (float*)carve((size_t)P_ * D_ * 4);
  float* buf1 = (float*)carve((size_t)P_ * DFF_ * 4);
  float* ff   = (float*)carve((size_t)P_ * DFF_ * 4);
  float* pbuf = (float*)carve((size_t)P_ * D_ * 4);
  int* node   = (int*)carve(P_ * 4);
  int* order  = (int*)carve(P_ * 4);
  int* invord = (int*)carve(P_ * 4);
  int* offs   = (int*)carve(NN_ * 4);
  int* cnts   = (int*)carve(NN_ * 4);
  int* tnode  = (int*)carve(MAXT_ * 4);
  int* tstart = (int*)carve(MAXT_ * 4);
  int* tend   = (int*)carve(MAXT_ * 4);
  int* ntiles = (int*)carve(4);

  encode_kernel<<<P_, 256, 0, stream>>>(query_keys, writer_keys, key_proj_w, key_proj_b,
                                        class_embed, role_embed, start_node_embed,
                                        input_ln_g, input_ln_b, query_start_nodes,
                                        writer_labels, writer_start_nodes, h, node);

  for (int hop = 0; hop < HOPS_; ++hop) {
    sort_kernel<<<1, 256, 0, stream>>>(node, order, invord, offs, cnts,
                                       tnode, tstart, tend, ntiles);
    ln_affine<<<P_ / 4, 256, 0, stream>>>(h, ln1_g, ln1_b, node, order, x);
    glin<256, 768, 64, 0, 0, 1, 1, 0><<<dim3(MAXT_, 12), 256, 0, stream>>>(
        x, wqkv, bqkv, buf1, nullptr, nullptr, order, invord, tnode, tstart, tend,
        ntiles);
    attn_kernel<<<dim3(P_ / 32, NH_), 256, 0, stream>>>(buf1, node, order, offs,
                                                        cnts, x /*ao, sorted*/);
    glin<256, 256, 64, 0, 1, 1, 1, 0><<<dim3(MAXT_, 4), 256, 0, stream>>>(
        x, wo, bo, h, nullptr, nullptr, order, invord, tnode, tstart, tend, ntiles);
    ln_affine<<<P_ / 4, 256, 0, stream>>>(h, ln2_g, ln2_b, node, order, x);
    glin<256, 1024, 64, 1, 0, 1, 1, 0><<<dim3(MAXT_, 16), 256, 0, stream>>>(
        x, w_fc1, b_fc1, ff, nullptr, nullptr, order, invord, tnode, tstart, tend,
        ntiles);
    glin<1024, 256, 64, 0, 1, 1, 2, 0><<<dim3(MAXT_, 4, 2), 256, 0, stream>>>(
        ff, w_fc2, b_fc2, h, pbuf, nullptr, order, invord, tnode, tstart, tend,
        ntiles);
    // delta = (h + pbuf) @ delta_w + delta_b   (dense, packet space, XMODE=1)
    glin<256, 256, 64, 0, 0, 0, 1, 1><<<dim3(P_ / 64, 4), 256, 0, stream>>>(
        h, delta_w, delta_b, buf1 /*delta out*/, nullptr, pbuf, order, invord,
        tnode, tstart, tend, ntiles);
    route_kernel<<<P_, 256, 0, stream>>>(h, pbuf, invord, dir_w, dir_b, address_table,
                                         mag_w, mag_b, buf1, node);
  }

  out_kernel<<<P_, 256, 0, stream>>>(h, out_w, out_b, (float*)d_out);
}